// Round 9
// baseline (549.065 us; speedup 1.0000x reference)
//
#include <hip/hip_runtime.h>

#define C_DIM 128
#define HW_DIM 6144

typedef __attribute__((ext_vector_type(8))) short short8;
typedef __attribute__((ext_vector_type(4))) float f32x4;

static __device__ __forceinline__ unsigned short f2bf(float x) {
    unsigned int u = __builtin_bit_cast(unsigned int, x);
    u = (u + 0x7FFFu + ((u >> 16) & 1u)) >> 16;
    return (unsigned short)u;
}

static __device__ __forceinline__ f32x4 mfma_bf16(short8 a, short8 b, f32x4 c) {
    return __builtin_amdgcn_mfma_f32_16x16x32_bf16(a, b, c, 0, 0, 0);
}

// ---------------------------------------------------------------------------
// Fused 1x1-conv + BN(inference) + LeakyReLU(0.1) GEMM.  (round-4 proven)
// ---------------------------------------------------------------------------
template<int IN_LAYOUT, int OUT_MODE>
__global__ __launch_bounds__(256)
void conv_bn_lrelu(const float* __restrict__ X, const float* __restrict__ W,
                   const float* __restrict__ G, const float* __restrict__ Bv,
                   void* __restrict__ outp, const float* __restrict__ resid,
                   float oscale)
{
    __shared__ float Xs[32][33];     // [c][p], +1 pad
    __shared__ float Wt[32][132];    // [c][o], row stride 132 keeps 16B align
    const int t  = threadIdx.x;
    const int b  = blockIdx.y;
    const int p0 = blockIdx.x * 32;
    const int p  = t & 15;           // positions p and p+16
    const int og = t >> 4;           // 16 groups x 8 out-ch
    const int ob = og * 8;

    float acc0[8], acc1[8];
#pragma unroll
    for (int i = 0; i < 8; ++i) { acc0[i] = 0.f; acc1[i] = 0.f; }

    const float* Xb = X + (size_t)b * C_DIM * HW_DIM;

    for (int c0 = 0; c0 < C_DIM; c0 += 32) {
#pragma unroll
        for (int i = 0; i < 4; ++i) {
            int idx = t + 256 * i;
            if (IN_LAYOUT == 0) {
                int cc = idx >> 5, pp = idx & 31;
                Xs[cc][pp] = Xb[(size_t)(c0 + cc) * HW_DIM + p0 + pp];
            } else {
                int pp = idx >> 5, cc = idx & 31;
                Xs[cc][pp] = Xb[(size_t)(p0 + pp) * C_DIM + c0 + cc];
            }
        }
#pragma unroll
        for (int i = 0; i < 16; ++i) {
            int idx = t + 256 * i;
            int o = idx >> 5, cc = idx & 31;
            Wt[cc][o] = W[o * C_DIM + c0 + cc];
        }
        __syncthreads();
#pragma unroll
        for (int cc = 0; cc < 32; ++cc) {
            float xv0 = Xs[cc][p];
            float xv1 = Xs[cc][p + 16];
            const float4* wrow = (const float4*)&Wt[cc][ob];
#pragma unroll
            for (int j = 0; j < 2; ++j) {
                float4 w4 = wrow[j];
                acc0[4 * j + 0] = fmaf(w4.x, xv0, acc0[4 * j + 0]);
                acc0[4 * j + 1] = fmaf(w4.y, xv0, acc0[4 * j + 1]);
                acc0[4 * j + 2] = fmaf(w4.z, xv0, acc0[4 * j + 2]);
                acc0[4 * j + 3] = fmaf(w4.w, xv0, acc0[4 * j + 3]);
                acc1[4 * j + 0] = fmaf(w4.x, xv1, acc1[4 * j + 0]);
                acc1[4 * j + 1] = fmaf(w4.y, xv1, acc1[4 * j + 1]);
                acc1[4 * j + 2] = fmaf(w4.z, xv1, acc1[4 * j + 2]);
                acc1[4 * j + 3] = fmaf(w4.w, xv1, acc1[4 * j + 3]);
            }
        }
        __syncthreads();
    }

    const float BNRS = 0.99999500003749972f;  // 1/sqrt(1 + 1e-5)
#pragma unroll
    for (int i = 0; i < 8; ++i) {
        int o = ob + i;
        float s = G[o] * BNRS, bb = Bv[o];
        float y0 = fmaf(acc0[i], s, bb);
        float y1 = fmaf(acc1[i], s, bb);
        acc0[i] = y0 > 0.f ? y0 : 0.1f * y0;
        acc1[i] = y1 > 0.f ? y1 : 0.1f * y1;
    }

    if constexpr (OUT_MODE == 0) {
        float* O = (float*)outp;
#pragma unroll
        for (int i = 0; i < 8; ++i) {
            O[((size_t)b * C_DIM + ob + i) * HW_DIM + p0 + p]      = acc0[i];
            O[((size_t)b * C_DIM + ob + i) * HW_DIM + p0 + p + 16] = acc1[i];
        }
    } else if constexpr (OUT_MODE == 1) {
        unsigned short* O = (unsigned short*)outp;
        unsigned int u0[4], u1[4];
#pragma unroll
        for (int j = 0; j < 4; ++j) {
            u0[j] = (unsigned int)f2bf(acc0[2 * j] * oscale) |
                    ((unsigned int)f2bf(acc0[2 * j + 1] * oscale) << 16);
            u1[j] = (unsigned int)f2bf(acc1[2 * j] * oscale) |
                    ((unsigned int)f2bf(acc1[2 * j + 1] * oscale) << 16);
        }
        *(uint4*)(O + ((size_t)b * HW_DIM + p0 + p) * C_DIM + ob) =
            make_uint4(u0[0], u0[1], u0[2], u0[3]);
        *(uint4*)(O + ((size_t)b * HW_DIM + p0 + p + 16) * C_DIM + ob) =
            make_uint4(u1[0], u1[1], u1[2], u1[3]);
    } else if constexpr (OUT_MODE == 2) {
        unsigned short* O = (unsigned short*)outp;
#pragma unroll
        for (int i = 0; i < 8; ++i) {
            O[((size_t)b * C_DIM + ob + i) * HW_DIM + p0 + p]      = f2bf(acc0[i]);
            O[((size_t)b * C_DIM + ob + i) * HW_DIM + p0 + p + 16] = f2bf(acc1[i]);
        }
    } else {
        float* O = (float*)outp;
#pragma unroll
        for (int i = 0; i < 8; ++i) {
            size_t i0 = ((size_t)b * C_DIM + ob + i) * HW_DIM + p0 + p;
            O[i0]      = acc0[i] + resid[i0];
            O[i0 + 16] = acc1[i] + resid[i0 + 16];
        }
    }
}

// ---------------------------------------------------------------------------
// Flash attention, 64 q-rows per block (4 waves x 16 rows), NO split-K.
// 256-thread blocks (r4-proven launch shape). Binding constraint (measured
// r2/r4): aggregate cache-read bytes = (#q-blocks) x 3 MB of K+V.
// 192 blocks -> 576 MB, a 4x cut vs r4's 2.3 GB. Waves share the K/V tile
// stream -> L1/L2 catch reuse; XCD-batch swizzle keeps each XCD on one
// batch's 3 MB (< 4 MB L2). Fixed-shift softmax (r4-proven), barrier-free.
// Q: [b][pos][c] bf16 (pre-scaled by C^-0.5 * log2e), K: [b][pos][c] bf16,
// V: [b][c][pos] bf16. Output ctx: [b][pos][c] fp32.
// ---------------------------------------------------------------------------
__global__ __launch_bounds__(256)
void flash_attn(const unsigned short* __restrict__ Q,
                const unsigned short* __restrict__ K,
                const unsigned short* __restrict__ V,
                float* __restrict__ ctx)
{
    __shared__ __align__(16) unsigned short Plds[4][16][72];
    const int tid  = threadIdx.x;
    const int wave = tid >> 6;         // 0..3
    const int lane = tid & 63;
    const int quad = lane >> 4;
    const int l16  = lane & 15;

    const int bid  = blockIdx.x;       // 0..191
    const int xcd  = bid & 7;
    const int b    = xcd >> 2;
    const int qblk = (bid >> 3) * 4 + (xcd & 3);   // 0..95
    const int q0   = qblk * 64 + wave * 16;

    const unsigned short* Qb = Q + (size_t)b * HW_DIM * C_DIM;
    const unsigned short* Kb = K + (size_t)b * HW_DIM * C_DIM;
    const unsigned short* Vb = V + (size_t)b * C_DIM * HW_DIM;

    // Q fragments, register-resident for the whole K loop
    short8 qf[4];
#pragma unroll
    for (int s = 0; s < 4; ++s)
        qf[s] = *(const short8*)&Qb[(size_t)(q0 + l16) * C_DIM + s * 32 + quad * 8];

    f32x4 O[8];
#pragma unroll
    for (int h = 0; h < 8; ++h) O[h] = (f32x4){0.f, 0.f, 0.f, 0.f};
    float lsum[4] = {0.f, 0.f, 0.f, 0.f};   // per-lane partial row sums

    for (int kb = 0; kb < HW_DIM; kb += 64) {
        // ---- batched K-fragment loads (16 independent loads in flight) ----
        short8 kf[4][4];
#pragma unroll
        for (int n = 0; n < 4; ++n) {
            const unsigned short* krow =
                &Kb[(size_t)(kb + n * 16 + l16) * C_DIM + quad * 8];
#pragma unroll
            for (int s = 0; s < 4; ++s)
                kf[n][s] = *(const short8*)(krow + s * 32);
        }
        // ---- S = Q * K^T ----
        f32x4 S[4];
#pragma unroll
        for (int n = 0; n < 4; ++n) S[n] = (f32x4){0.f, 0.f, 0.f, 0.f};
#pragma unroll
        for (int n = 0; n < 4; ++n)
#pragma unroll
            for (int s = 0; s < 4; ++s)
                S[n] = mfma_bf16(qf[s], kf[n][s], S[n]);

        // ---- fixed-shift softmax: e = exp2(S); P -> LDS (C/D -> A layout,
        //      per-wave region, wave-ordered DS => no barrier) ----
#pragma unroll
        for (int n = 0; n < 4; ++n)
#pragma unroll
            for (int r = 0; r < 4; ++r) {
                float e = __builtin_amdgcn_exp2f(S[n][r]);
                lsum[r] += e;
                Plds[wave][quad * 4 + r][n * 16 + l16] = f2bf(e);
            }

        // ---- batched V-fragment loads (issued before P read-back) ----
        short8 vf[8][2];
#pragma unroll
        for (int h = 0; h < 8; ++h) {
            const unsigned short* vrow =
                &Vb[(size_t)(h * 16 + l16) * HW_DIM + kb + quad * 8];
            vf[h][0] = *(const short8*)(vrow);
            vf[h][1] = *(const short8*)(vrow + 32);
        }
        short8 pa0 = *(const short8*)&Plds[wave][l16][quad * 8];
        short8 pa1 = *(const short8*)&Plds[wave][l16][32 + quad * 8];

        // ---- O += P * V^T ----
#pragma unroll
        for (int h = 0; h < 8; ++h) {
            O[h] = mfma_bf16(pa0, vf[h][0], O[h]);
            O[h] = mfma_bf16(pa1, vf[h][1], O[h]);
        }
    }

    // ---- one-time row-sum reduction over the 16 lanes of each row ----
#pragma unroll
    for (int off = 1; off < 16; off <<= 1)
#pragma unroll
        for (int r = 0; r < 4; ++r)
            lsum[r] += __shfl_xor(lsum[r], off, 64);

    // ---- epilogue: normalize, write ctx [b][pos][c] fp32 directly ----
#pragma unroll
    for (int r = 0; r < 4; ++r) {
        float inv = 1.f / lsum[r];
        size_t row = (size_t)b * HW_DIM + q0 + quad * 4 + r;
#pragma unroll
        for (int h = 0; h < 8; ++h)
            ctx[row * C_DIM + h * 16 + l16] = O[h][r] * inv;
    }
}

// ---------------------------------------------------------------------------
extern "C" void kernel_launch(void* const* d_in, const int* in_sizes, int n_in,
                              void* d_out, int out_size, void* d_ws, size_t ws_size,
                              hipStream_t stream)
{
    const float* query = (const float*)d_in[0];
    const float* key   = (const float*)d_in[1];
    const float* q_w1 = (const float*)d_in[2];
    const float* q_g1 = (const float*)d_in[3];
    const float* q_b1 = (const float*)d_in[4];
    const float* q_w2 = (const float*)d_in[5];
    const float* q_g2 = (const float*)d_in[6];
    const float* q_b2 = (const float*)d_in[7];
    const float* k_w1 = (const float*)d_in[8];
    const float* k_g1 = (const float*)d_in[9];
    const float* k_b1 = (const float*)d_in[10];
    const float* k_w2 = (const float*)d_in[11];
    const float* k_g2 = (const float*)d_in[12];
    const float* k_b2 = (const float*)d_in[13];
    const float* v_w  = (const float*)d_in[14];
    const float* v_g  = (const float*)d_in[15];
    const float* v_b  = (const float*)d_in[16];
    const float* o_w  = (const float*)d_in[17];
    const float* o_g  = (const float*)d_in[18];
    const float* o_b  = (const float*)d_in[19];

    char* ws = (char*)d_ws;
    float*          y1  = (float*)ws;                                   // 6 MB
    unsigned short* Qbf = (unsigned short*)(ws + 6291456);              // 3 MB
    unsigned short* Kbf = (unsigned short*)(ws + 6291456 + 3145728);    // 3 MB
    unsigned short* Vbf = (unsigned short*)(ws + 6291456 + 2 * 3145728);// 3 MB
    float*          ctx = (float*)(ws + 6291456 + 3 * 3145728);         // 6 MB
    float* outp = (float*)d_out;

    // fold softmax scale (C^-1/2) and log2(e) into Q
    const float qscale = 0.08838834764831845f * 1.44269504088896340f;

    dim3 cgrid(HW_DIM / 32, 2), cblk(256);
    hipLaunchKernelGGL((conv_bn_lrelu<0, 0>), cgrid, cblk, 0, stream,
                       query, q_w1, q_g1, q_b1, (void*)y1, nullptr, 1.0f);
    hipLaunchKernelGGL((conv_bn_lrelu<0, 1>), cgrid, cblk, 0, stream,
                       y1, q_w2, q_g2, q_b2, (void*)Qbf, nullptr, qscale);
    hipLaunchKernelGGL((conv_bn_lrelu<0, 0>), cgrid, cblk, 0, stream,
                       key, k_w1, k_g1, k_b1, (void*)y1, nullptr, 1.0f);
    hipLaunchKernelGGL((conv_bn_lrelu<0, 1>), cgrid, cblk, 0, stream,
                       y1, k_w2, k_g2, k_b2, (void*)Kbf, nullptr, 1.0f);
    hipLaunchKernelGGL((conv_bn_lrelu<0, 2>), cgrid, cblk, 0, stream,
                       key, v_w, v_g, v_b, (void*)Vbf, nullptr, 1.0f);

    // Flash attention: 64 q-rows/block, 4 waves, grid 192 (XCD-affine).
    hipLaunchKernelGGL(flash_attn, dim3((HW_DIM / 64) * 2), dim3(256), 0, stream,
                       Qbf, Kbf, Vbf, ctx);

    hipLaunchKernelGGL((conv_bn_lrelu<1, 3>), cgrid, cblk, 0, stream,
                       ctx, o_w, o_g, o_b, (void*)outp, query, 1.0f);
}

// Round 10
// 283.708 us; speedup vs baseline: 1.9353x; 1.9353x over previous
//
#include <hip/hip_runtime.h>

#define C_DIM 128
#define HW_DIM 6144

typedef __attribute__((ext_vector_type(8))) short short8;
typedef __attribute__((ext_vector_type(4))) float f32x4;

static __device__ __forceinline__ unsigned short f2bf(float x) {
    unsigned int u = __builtin_bit_cast(unsigned int, x);
    u = (u + 0x7FFFu + ((u >> 16) & 1u)) >> 16;
    return (unsigned short)u;
}

static __device__ __forceinline__ f32x4 mfma_bf16(short8 a, short8 b, f32x4 c) {
    return __builtin_amdgcn_mfma_f32_16x16x32_bf16(a, b, c, 0, 0, 0);
}

// ---------------------------------------------------------------------------
// Fused 1x1-conv + BN(inference) + LeakyReLU(0.1) GEMM.  (r4/r9 proven)
// ---------------------------------------------------------------------------
template<int IN_LAYOUT, int OUT_MODE>
__global__ __launch_bounds__(256)
void conv_bn_lrelu(const float* __restrict__ X, const float* __restrict__ W,
                   const float* __restrict__ G, const float* __restrict__ Bv,
                   void* __restrict__ outp, const float* __restrict__ resid,
                   float oscale)
{
    __shared__ float Xs[32][33];     // [c][p], +1 pad
    __shared__ float Wt[32][132];    // [c][o], row stride 132 keeps 16B align
    const int t  = threadIdx.x;
    const int b  = blockIdx.y;
    const int p0 = blockIdx.x * 32;
    const int p  = t & 15;           // positions p and p+16
    const int og = t >> 4;           // 16 groups x 8 out-ch
    const int ob = og * 8;

    float acc0[8], acc1[8];
#pragma unroll
    for (int i = 0; i < 8; ++i) { acc0[i] = 0.f; acc1[i] = 0.f; }

    const float* Xb = X + (size_t)b * C_DIM * HW_DIM;

    for (int c0 = 0; c0 < C_DIM; c0 += 32) {
#pragma unroll
        for (int i = 0; i < 4; ++i) {
            int idx = t + 256 * i;
            if (IN_LAYOUT == 0) {
                int cc = idx >> 5, pp = idx & 31;
                Xs[cc][pp] = Xb[(size_t)(c0 + cc) * HW_DIM + p0 + pp];
            } else {
                int pp = idx >> 5, cc = idx & 31;
                Xs[cc][pp] = Xb[(size_t)(p0 + pp) * C_DIM + c0 + cc];
            }
        }
#pragma unroll
        for (int i = 0; i < 16; ++i) {
            int idx = t + 256 * i;
            int o = idx >> 5, cc = idx & 31;
            Wt[cc][o] = W[o * C_DIM + c0 + cc];
        }
        __syncthreads();
#pragma unroll
        for (int cc = 0; cc < 32; ++cc) {
            float xv0 = Xs[cc][p];
            float xv1 = Xs[cc][p + 16];
            const float4* wrow = (const float4*)&Wt[cc][ob];
#pragma unroll
            for (int j = 0; j < 2; ++j) {
                float4 w4 = wrow[j];
                acc0[4 * j + 0] = fmaf(w4.x, xv0, acc0[4 * j + 0]);
                acc0[4 * j + 1] = fmaf(w4.y, xv0, acc0[4 * j + 1]);
                acc0[4 * j + 2] = fmaf(w4.z, xv0, acc0[4 * j + 2]);
                acc0[4 * j + 3] = fmaf(w4.w, xv0, acc0[4 * j + 3]);
                acc1[4 * j + 0] = fmaf(w4.x, xv1, acc1[4 * j + 0]);
                acc1[4 * j + 1] = fmaf(w4.y, xv1, acc1[4 * j + 1]);
                acc1[4 * j + 2] = fmaf(w4.z, xv1, acc1[4 * j + 2]);
                acc1[4 * j + 3] = fmaf(w4.w, xv1, acc1[4 * j + 3]);
            }
        }
        __syncthreads();
    }

    const float BNRS = 0.99999500003749972f;  // 1/sqrt(1 + 1e-5)
#pragma unroll
    for (int i = 0; i < 8; ++i) {
        int o = ob + i;
        float s = G[o] * BNRS, bb = Bv[o];
        float y0 = fmaf(acc0[i], s, bb);
        float y1 = fmaf(acc1[i], s, bb);
        acc0[i] = y0 > 0.f ? y0 : 0.1f * y0;
        acc1[i] = y1 > 0.f ? y1 : 0.1f * y1;
    }

    if constexpr (OUT_MODE == 0) {
        float* O = (float*)outp;
#pragma unroll
        for (int i = 0; i < 8; ++i) {
            O[((size_t)b * C_DIM + ob + i) * HW_DIM + p0 + p]      = acc0[i];
            O[((size_t)b * C_DIM + ob + i) * HW_DIM + p0 + p + 16] = acc1[i];
        }
    } else if constexpr (OUT_MODE == 1) {
        unsigned short* O = (unsigned short*)outp;
        unsigned int u0[4], u1[4];
#pragma unroll
        for (int j = 0; j < 4; ++j) {
            u0[j] = (unsigned int)f2bf(acc0[2 * j] * oscale) |
                    ((unsigned int)f2bf(acc0[2 * j + 1] * oscale) << 16);
            u1[j] = (unsigned int)f2bf(acc1[2 * j] * oscale) |
                    ((unsigned int)f2bf(acc1[2 * j + 1] * oscale) << 16);
        }
        *(uint4*)(O + ((size_t)b * HW_DIM + p0 + p) * C_DIM + ob) =
            make_uint4(u0[0], u0[1], u0[2], u0[3]);
        *(uint4*)(O + ((size_t)b * HW_DIM + p0 + p + 16) * C_DIM + ob) =
            make_uint4(u1[0], u1[1], u1[2], u1[3]);
    } else if constexpr (OUT_MODE == 2) {
        unsigned short* O = (unsigned short*)outp;
#pragma unroll
        for (int i = 0; i < 8; ++i) {
            O[((size_t)b * C_DIM + ob + i) * HW_DIM + p0 + p]      = f2bf(acc0[i]);
            O[((size_t)b * C_DIM + ob + i) * HW_DIM + p0 + p + 16] = f2bf(acc1[i]);
        }
    } else {
        float* O = (float*)outp;
#pragma unroll
        for (int i = 0; i < 8; ++i) {
            size_t i0 = ((size_t)b * C_DIM + ob + i) * HW_DIM + p0 + p;
            O[i0]      = acc0[i] + resid[i0];
            O[i0 + 16] = acc1[i] + resid[i0 + 16];
        }
    }
}

// ---------------------------------------------------------------------------
// Flash attention with LDS-staged, double-buffered K/V tiles.
// Measured r1/r2/r4/r9: total VMEM-issued load bytes is the binding resource
// (~14 B/cy/CU; 2.3 GB of per-wave K/V fragment loads -> 270-380 us in every
// register-direct config). Fix: stage each 64-pos K-tile (16 KB) + V-tile
// (16 KB) into LDS ONCE per block (cooperative, double-buffered, loads for
// tile k+1 in flight while computing tile k); fragment reads become
// ds_read_b128 on the separate DS pipe (128 B/cy/CU). VMEM issued bytes drop
// 2.3 GB -> 576 MB (192 blocks x 3 MB). LDS layouts padded: K [64][136],
// V [128][72] -> <=2-way bank aliasing (free) for staging and frag reads.
// Block: 256 thr = 4 waves x 16 q-rows (64 q-rows/block), grid 192,
// XCD-batch swizzle (each XCD's K/V = 3 MB < 4 MB L2). Fixed-shift softmax.
// Q: [b][pos][c] bf16 (pre-scaled by C^-0.5 * log2e), K: [b][pos][c] bf16,
// V: [b][c][pos] bf16. Output ctx: [b][pos][c] fp32. LDS total 79 KB.
// ---------------------------------------------------------------------------
__global__ __launch_bounds__(256)
void flash_attn(const unsigned short* __restrict__ Q,
                const unsigned short* __restrict__ K,
                const unsigned short* __restrict__ V,
                float* __restrict__ ctx)
{
    __shared__ __align__(16) unsigned short Kt[2][64][136];   // 2 x 17.0 KB
    __shared__ __align__(16) unsigned short Vt[2][128][72];   // 2 x 18.0 KB
    __shared__ __align__(16) unsigned short Plds[4][16][72];  // 9.0 KB
    const int tid  = threadIdx.x;
    const int wave = tid >> 6;         // 0..3
    const int lane = tid & 63;
    const int quad = lane >> 4;
    const int l16  = lane & 15;

    const int bid  = blockIdx.x;       // 0..191
    const int xcd  = bid & 7;
    const int b    = xcd >> 2;
    const int qblk = (bid >> 3) * 4 + (xcd & 3);   // 0..95
    const int q0   = qblk * 64 + wave * 16;

    const unsigned short* Qb = Q + (size_t)b * HW_DIM * C_DIM;
    const unsigned short* Kb = K + (size_t)b * HW_DIM * C_DIM;
    const unsigned short* Vb = V + (size_t)b * C_DIM * HW_DIM;

    // Q fragments, register-resident for the whole K loop
    short8 qf[4];
#pragma unroll
    for (int s = 0; s < 4; ++s)
        qf[s] = *(const short8*)&Qb[(size_t)(q0 + l16) * C_DIM + s * 32 + quad * 8];

    f32x4 O[8];
#pragma unroll
    for (int h = 0; h < 8; ++h) O[h] = (f32x4){0.f, 0.f, 0.f, 0.f};
    float lsum[4] = {0.f, 0.f, 0.f, 0.f};

    // ---- staging: 256 threads move 16 KB K + 16 KB V per tile.
    // K chunk ck = tid + 256j: pos = ck>>4, c16 = ck&15 (16B each)
    // V chunk cv = tid + 256j: ch  = cv>>3, p8  = cv&7  (16B each)
    uint4 kst[4], vst[4];
#pragma unroll
    for (int j = 0; j < 4; ++j) {
        int ck = tid + 256 * j;
        kst[j] = *(const uint4*)&Kb[(size_t)(ck >> 4) * C_DIM + (ck & 15) * 8];
        vst[j] = *(const uint4*)&Vb[(size_t)(ck >> 3) * HW_DIM + (ck & 7) * 8];
    }
#pragma unroll
    for (int j = 0; j < 4; ++j) {
        int ck = tid + 256 * j;
        *(uint4*)&Kt[0][ck >> 4][(ck & 15) * 8] = kst[j];
        *(uint4*)&Vt[0][ck >> 3][(ck & 7) * 8]  = vst[j];
    }

    for (int it = 0; it < HW_DIM / 64; ++it) {
        const int cur = it & 1;
        __syncthreads();   // buf[cur] writes visible; buf[cur^1] reads done

        // issue next tile's global loads (consumed at iter end -> overlap)
        const int kb2 = (it + 1) * 64;
        if (kb2 < HW_DIM) {
#pragma unroll
            for (int j = 0; j < 4; ++j) {
                int ck = tid + 256 * j;
                kst[j] = *(const uint4*)
                    &Kb[(size_t)(kb2 + (ck >> 4)) * C_DIM + (ck & 15) * 8];
                vst[j] = *(const uint4*)
                    &Vb[(size_t)(ck >> 3) * HW_DIM + kb2 + (ck & 7) * 8];
            }
        }

        // ---- S = Q * K^T from LDS ----
        f32x4 S[4];
#pragma unroll
        for (int n = 0; n < 4; ++n) S[n] = (f32x4){0.f, 0.f, 0.f, 0.f};
#pragma unroll
        for (int n = 0; n < 4; ++n)
#pragma unroll
            for (int s = 0; s < 4; ++s) {
                short8 kf = *(const short8*)
                    &Kt[cur][n * 16 + l16][s * 32 + quad * 8];
                S[n] = mfma_bf16(qf[s], kf, S[n]);
            }

        // ---- fixed-shift softmax; P -> per-wave LDS (C/D -> A layout) ----
#pragma unroll
        for (int n = 0; n < 4; ++n)
#pragma unroll
            for (int r = 0; r < 4; ++r) {
                float e = __builtin_amdgcn_exp2f(S[n][r]);
                lsum[r] += e;
                Plds[wave][quad * 4 + r][n * 16 + l16] = f2bf(e);
            }
        short8 pa0 = *(const short8*)&Plds[wave][l16][quad * 8];
        short8 pa1 = *(const short8*)&Plds[wave][l16][32 + quad * 8];

        // ---- O += P * V^T from LDS ----
#pragma unroll
        for (int h = 0; h < 8; ++h) {
            short8 v0 = *(const short8*)&Vt[cur][h * 16 + l16][quad * 8];
            short8 v1 = *(const short8*)&Vt[cur][h * 16 + l16][32 + quad * 8];
            O[h] = mfma_bf16(pa0, v0, O[h]);
            O[h] = mfma_bf16(pa1, v1, O[h]);
        }

        // ---- write staged regs into the other buffer ----
        if (kb2 < HW_DIM) {
            const int nxt = cur ^ 1;
#pragma unroll
            for (int j = 0; j < 4; ++j) {
                int ck = tid + 256 * j;
                *(uint4*)&Kt[nxt][ck >> 4][(ck & 15) * 8] = kst[j];
                *(uint4*)&Vt[nxt][ck >> 3][(ck & 7) * 8]  = vst[j];
            }
        }
    }

    // ---- one-time row-sum reduction over the 16 lanes of each row ----
#pragma unroll
    for (int off = 1; off < 16; off <<= 1)
#pragma unroll
        for (int r = 0; r < 4; ++r)
            lsum[r] += __shfl_xor(lsum[r], off, 64);

    // ---- epilogue: normalize, write ctx [b][pos][c] fp32 ----
#pragma unroll
    for (int r = 0; r < 4; ++r) {
        float inv = 1.f / lsum[r];
        size_t row = (size_t)b * HW_DIM + q0 + quad * 4 + r;
#pragma unroll
        for (int h = 0; h < 8; ++h)
            ctx[row * C_DIM + h * 16 + l16] = O[h][r] * inv;
    }
}

// ---------------------------------------------------------------------------
extern "C" void kernel_launch(void* const* d_in, const int* in_sizes, int n_in,
                              void* d_out, int out_size, void* d_ws, size_t ws_size,
                              hipStream_t stream)
{
    const float* query = (const float*)d_in[0];
    const float* key   = (const float*)d_in[1];
    const float* q_w1 = (const float*)d_in[2];
    const float* q_g1 = (const float*)d_in[3];
    const float* q_b1 = (const float*)d_in[4];
    const float* q_w2 = (const float*)d_in[5];
    const float* q_g2 = (const float*)d_in[6];
    const float* q_b2 = (const float*)d_in[7];
    const float* k_w1 = (const float*)d_in[8];
    const float* k_g1 = (const float*)d_in[9];
    const float* k_b1 = (const float*)d_in[10];
    const float* k_w2 = (const float*)d_in[11];
    const float* k_g2 = (const float*)d_in[12];
    const float* k_b2 = (const float*)d_in[13];
    const float* v_w  = (const float*)d_in[14];
    const float* v_g  = (const float*)d_in[15];
    const float* v_b  = (const float*)d_in[16];
    const float* o_w  = (const float*)d_in[17];
    const float* o_g  = (const float*)d_in[18];
    const float* o_b  = (const float*)d_in[19];

    char* ws = (char*)d_ws;
    float*          y1  = (float*)ws;                                   // 6 MB
    unsigned short* Qbf = (unsigned short*)(ws + 6291456);              // 3 MB
    unsigned short* Kbf = (unsigned short*)(ws + 6291456 + 3145728);    // 3 MB
    unsigned short* Vbf = (unsigned short*)(ws + 6291456 + 2 * 3145728);// 3 MB
    float*          ctx = (float*)(ws + 6291456 + 3 * 3145728);         // 6 MB
    float* outp = (float*)d_out;

    // fold softmax scale (C^-1/2) and log2(e) into Q
    const float qscale = 0.08838834764831845f * 1.44269504088896340f;

    dim3 cgrid(HW_DIM / 32, 2), cblk(256);
    hipLaunchKernelGGL((conv_bn_lrelu<0, 0>), cgrid, cblk, 0, stream,
                       query, q_w1, q_g1, q_b1, (void*)y1, nullptr, 1.0f);
    hipLaunchKernelGGL((conv_bn_lrelu<0, 1>), cgrid, cblk, 0, stream,
                       y1, q_w2, q_g2, q_b2, (void*)Qbf, nullptr, qscale);
    hipLaunchKernelGGL((conv_bn_lrelu<0, 0>), cgrid, cblk, 0, stream,
                       key, k_w1, k_g1, k_b1, (void*)y1, nullptr, 1.0f);
    hipLaunchKernelGGL((conv_bn_lrelu<0, 1>), cgrid, cblk, 0, stream,
                       y1, k_w2, k_g2, k_b2, (void*)Kbf, nullptr, 1.0f);
    hipLaunchKernelGGL((conv_bn_lrelu<0, 2>), cgrid, cblk, 0, stream,
                       key, v_w, v_g, v_b, (void*)Vbf, nullptr, 1.0f);

    // Flash attention: 64 q-rows/block, LDS-staged K/V, grid 192 (XCD-affine).
    hipLaunchKernelGGL(flash_attn, dim3((HW_DIM / 64) * 2), dim3(256), 0, stream,
                       Qbf, Kbf, Vbf, ctx);

    hipLaunchKernelGGL((conv_bn_lrelu<1, 3>), cgrid, cblk, 0, stream,
                       ctx, o_w, o_g, o_b, (void*)outp, query, 1.0f);
}

// Round 11
// 258.273 us; speedup vs baseline: 2.1259x; 1.0985x over previous
//
#include <hip/hip_runtime.h>

#define C_DIM 128
#define HW_DIM 6144

typedef __attribute__((ext_vector_type(8))) short short8;
typedef __attribute__((ext_vector_type(4))) float f32x4;

static __device__ __forceinline__ unsigned short f2bf(float x) {
    unsigned int u = __builtin_bit_cast(unsigned int, x);
    u = (u + 0x7FFFu + ((u >> 16) & 1u)) >> 16;
    return (unsigned short)u;
}

static __device__ __forceinline__ f32x4 mfma_bf16(short8 a, short8 b, f32x4 c) {
    return __builtin_amdgcn_mfma_f32_16x16x32_bf16(a, b, c, 0, 0, 0);
}

// ---------------------------------------------------------------------------
// Fused 1x1-conv + BN + LeakyReLU GEMM, v2: 4-pos x 4-out thread tiles so
// both LDS operand reads are float4 (b128) and mostly bank-broadcast.
// IN_MODE : 0 = X[b][c][hw] fp32, 1 = X[b][hw][c] fp32,
//           2 = COMBINE: x = (X[pos][c] + X2[pos][c]) * invL[pos]  (split-K)
// OUT_MODE: 0 = fp32 [b][c][hw]
//           1 = bf16 [b][pos][c] scaled by oscale (Q/K layout)
//           2 = bf16 [b][c][pos]                  (V layout)
//           3 = fp32 [b][c][hw] + residual        (final output)
// ---------------------------------------------------------------------------
template<int IN_MODE, int OUT_MODE>
__global__ __launch_bounds__(256)
void conv_bn_lrelu(const float* __restrict__ X, const float* __restrict__ X2,
                   const float* __restrict__ Lp0, const float* __restrict__ Lp1,
                   const float* __restrict__ W, const float* __restrict__ G,
                   const float* __restrict__ Bv, void* __restrict__ outp,
                   const float* __restrict__ resid, float oscale)
{
    __shared__ float Xs[32][36];     // [c][p], stride 36 keeps float4 align
    __shared__ float Wt[32][132];    // [c][o]
    __shared__ float invL[32];
    const int t  = threadIdx.x;
    const int b  = blockIdx.y;
    const int p0 = blockIdx.x * 32;
    const int pg = t & 7;            // pos group: positions pg*4 .. pg*4+3
    const int og = t >> 3;           // out group: out-ch og*4 .. og*4+3
    const int pb = pg * 4;
    const int ob = og * 4;

    if (IN_MODE == 2 && t < 32)
        invL[t] = 1.0f / (Lp0[(size_t)b * HW_DIM + p0 + t] +
                          Lp1[(size_t)b * HW_DIM + p0 + t]);
    if (IN_MODE == 2) __syncthreads();

    float acc[4][4];                 // [pos][out]
#pragma unroll
    for (int i = 0; i < 4; ++i)
#pragma unroll
        for (int j = 0; j < 4; ++j) acc[i][j] = 0.f;

    const float* Xb  = X  + (size_t)b * C_DIM * HW_DIM;
    const float* Xb2 = (IN_MODE == 2) ? X2 + (size_t)b * C_DIM * HW_DIM : nullptr;

    for (int c0 = 0; c0 < C_DIM; c0 += 32) {
#pragma unroll
        for (int i = 0; i < 4; ++i) {
            int idx = t + 256 * i;
            if (IN_MODE == 0) {
                int cc = idx >> 5, pp = idx & 31;
                Xs[cc][pp] = Xb[(size_t)(c0 + cc) * HW_DIM + p0 + pp];
            } else if (IN_MODE == 1) {
                int pp = idx >> 5, cc = idx & 31;
                Xs[cc][pp] = Xb[(size_t)(p0 + pp) * C_DIM + c0 + cc];
            } else {
                int pp = idx >> 5, cc = idx & 31;
                size_t gi = (size_t)(p0 + pp) * C_DIM + c0 + cc;
                Xs[cc][pp] = (Xb[gi] + Xb2[gi]) * invL[pp];
            }
        }
#pragma unroll
        for (int i = 0; i < 16; ++i) {
            int idx = t + 256 * i;
            int o = idx >> 5, cc = idx & 31;
            Wt[cc][o] = W[o * C_DIM + c0 + cc];
        }
        __syncthreads();
#pragma unroll
        for (int cc = 0; cc < 32; ++cc) {
            float4 xv = *(const float4*)&Xs[cc][pb];
            float4 wv = *(const float4*)&Wt[cc][ob];
            acc[0][0] = fmaf(xv.x, wv.x, acc[0][0]);
            acc[0][1] = fmaf(xv.x, wv.y, acc[0][1]);
            acc[0][2] = fmaf(xv.x, wv.z, acc[0][2]);
            acc[0][3] = fmaf(xv.x, wv.w, acc[0][3]);
            acc[1][0] = fmaf(xv.y, wv.x, acc[1][0]);
            acc[1][1] = fmaf(xv.y, wv.y, acc[1][1]);
            acc[1][2] = fmaf(xv.y, wv.z, acc[1][2]);
            acc[1][3] = fmaf(xv.y, wv.w, acc[1][3]);
            acc[2][0] = fmaf(xv.z, wv.x, acc[2][0]);
            acc[2][1] = fmaf(xv.z, wv.y, acc[2][1]);
            acc[2][2] = fmaf(xv.z, wv.z, acc[2][2]);
            acc[2][3] = fmaf(xv.z, wv.w, acc[2][3]);
            acc[3][0] = fmaf(xv.w, wv.x, acc[3][0]);
            acc[3][1] = fmaf(xv.w, wv.y, acc[3][1]);
            acc[3][2] = fmaf(xv.w, wv.z, acc[3][2]);
            acc[3][3] = fmaf(xv.w, wv.w, acc[3][3]);
        }
        __syncthreads();
    }

    const float BNRS = 0.99999500003749972f;  // 1/sqrt(1 + 1e-5)
#pragma unroll
    for (int j = 0; j < 4; ++j) {
        int o = ob + j;
        float s = G[o] * BNRS, bb = Bv[o];
#pragma unroll
        for (int i = 0; i < 4; ++i) {
            float y = fmaf(acc[i][j], s, bb);
            acc[i][j] = y > 0.f ? y : 0.1f * y;
        }
    }

    if constexpr (OUT_MODE == 0) {
        float* O = (float*)outp;
#pragma unroll
        for (int j = 0; j < 4; ++j)
            *(float4*)&O[((size_t)b * C_DIM + ob + j) * HW_DIM + p0 + pb] =
                make_float4(acc[0][j], acc[1][j], acc[2][j], acc[3][j]);
    } else if constexpr (OUT_MODE == 1) {
        unsigned short* O = (unsigned short*)outp;
#pragma unroll
        for (int i = 0; i < 4; ++i) {
            ushort4 u = { f2bf(acc[i][0] * oscale), f2bf(acc[i][1] * oscale),
                          f2bf(acc[i][2] * oscale), f2bf(acc[i][3] * oscale) };
            *(ushort4*)&O[((size_t)b * HW_DIM + p0 + pb + i) * C_DIM + ob] = u;
        }
    } else if constexpr (OUT_MODE == 2) {
        unsigned short* O = (unsigned short*)outp;
#pragma unroll
        for (int j = 0; j < 4; ++j) {
            ushort4 u = { f2bf(acc[0][j]), f2bf(acc[1][j]),
                          f2bf(acc[2][j]), f2bf(acc[3][j]) };
            *(ushort4*)&O[((size_t)b * C_DIM + ob + j) * HW_DIM + p0 + pb] = u;
        }
    } else {
        float* O = (float*)outp;
#pragma unroll
        for (int j = 0; j < 4; ++j) {
            size_t i0 = ((size_t)b * C_DIM + ob + j) * HW_DIM + p0 + pb;
            float4 rv = *(const float4*)&resid[i0];
            *(float4*)&O[i0] = make_float4(acc[0][j] + rv.x, acc[1][j] + rv.y,
                                           acc[2][j] + rv.z, acc[3][j] + rv.w);
        }
    }
}

// ---------------------------------------------------------------------------
// Flash attention v3: LDS-staged double-buffered K/V (r10-proven) + 2-way
// split-K + 32 q-rows per wave (2 row-tiles sharing every K/V fragment read).
// r10 accounting: per-block VMEM bytes (3 MB K+V @ ~33 GB/s/CU) was the
// binder (91 us floor). Here each block reads HALF of K/V (1.5 MB -> 47 us
// floor) for 128 q-rows (4 waves x 32). Grid 192 = 96 q-blocks x 2 k-halves.
// Fixed-shift softmax => split-K combine is a plain sum: blocks emit
// UNNORMALIZED O-partials + row-sum partials; the out-conv combines.
// Q: [b][pos][c] bf16 (pre-scaled by C^-0.5 * log2e), K: [b][pos][c] bf16,
// V: [b][c][pos] bf16. Po: [b][pos][c] fp32 partial, Lo: [b][pos] fp32.
// LDS 90 KB -> 1 block/CU.
// ---------------------------------------------------------------------------
__global__ __launch_bounds__(256)
void flash_attn(const unsigned short* __restrict__ Q,
                const unsigned short* __restrict__ K,
                const unsigned short* __restrict__ V,
                float* __restrict__ P0, float* __restrict__ P1,
                float* __restrict__ L0, float* __restrict__ L1)
{
    __shared__ __align__(16) unsigned short Kt[2][64][136];     // 34.0 KB
    __shared__ __align__(16) unsigned short Vt[2][128][72];     // 36.0 KB
    __shared__ __align__(16) unsigned short Plds[4][2][16][72]; // 18.0 KB
    const int tid  = threadIdx.x;
    const int wave = tid >> 6;
    const int lane = tid & 63;
    const int quad = lane >> 4;
    const int l16  = lane & 15;

    const int bid  = blockIdx.x;                   // 0..191
    const int xcd  = bid & 7;
    const int b    = xcd >> 2;
    const int idx  = (bid >> 3) * 4 + (xcd & 3);   // 0..95 within batch
    const int qblk = idx >> 1;                     // 0..47
    const int ks   = idx & 1;                      // k-half
    const int q0   = qblk * 128 + wave * 32;
    const int kbeg = ks * (HW_DIM / 2);

    float* __restrict__ Po = ks ? P1 : P0;
    float* __restrict__ Lo = ks ? L1 : L0;

    const unsigned short* Qb = Q + (size_t)b * HW_DIM * C_DIM;
    const unsigned short* Kb = K + (size_t)b * HW_DIM * C_DIM;
    const unsigned short* Vb = V + (size_t)b * C_DIM * HW_DIM;

    // Q fragments for 2 row-tiles, register-resident
    short8 qf[2][4];
#pragma unroll
    for (int rt = 0; rt < 2; ++rt)
#pragma unroll
        for (int s = 0; s < 4; ++s)
            qf[rt][s] = *(const short8*)
                &Qb[(size_t)(q0 + rt * 16 + l16) * C_DIM + s * 32 + quad * 8];

    f32x4 O[2][8];
#pragma unroll
    for (int rt = 0; rt < 2; ++rt)
#pragma unroll
        for (int h = 0; h < 8; ++h) O[rt][h] = (f32x4){0.f, 0.f, 0.f, 0.f};
    float lsum[2][4] = {{0.f,0.f,0.f,0.f},{0.f,0.f,0.f,0.f}};

    // initial tile staging (K: pos=ck>>4, c16=ck&15; V: ch=ck>>3, p8=ck&7)
    uint4 kst[4], vst[4];
#pragma unroll
    for (int j = 0; j < 4; ++j) {
        int ck = tid + 256 * j;
        kst[j] = *(const uint4*)&Kb[(size_t)(kbeg + (ck >> 4)) * C_DIM + (ck & 15) * 8];
        vst[j] = *(const uint4*)&Vb[(size_t)(ck >> 3) * HW_DIM + kbeg + (ck & 7) * 8];
    }
#pragma unroll
    for (int j = 0; j < 4; ++j) {
        int ck = tid + 256 * j;
        *(uint4*)&Kt[0][ck >> 4][(ck & 15) * 8] = kst[j];
        *(uint4*)&Vt[0][ck >> 3][(ck & 7) * 8]  = vst[j];
    }

    const int NIT = (HW_DIM / 2) / 64;   // 48
    for (int it = 0; it < NIT; ++it) {
        const int cur = it & 1;
        __syncthreads();

        const int kb2 = kbeg + (it + 1) * 64;
        if (it + 1 < NIT) {
#pragma unroll
            for (int j = 0; j < 4; ++j) {
                int ck = tid + 256 * j;
                kst[j] = *(const uint4*)
                    &Kb[(size_t)(kb2 + (ck >> 4)) * C_DIM + (ck & 15) * 8];
                vst[j] = *(const uint4*)
                    &Vb[(size_t)(ck >> 3) * HW_DIM + kb2 + (ck & 7) * 8];
            }
        }

        // ---- S = Q*K^T, both row-tiles share each K-fragment read ----
        f32x4 S[2][4];
#pragma unroll
        for (int rt = 0; rt < 2; ++rt)
#pragma unroll
            for (int n = 0; n < 4; ++n) S[rt][n] = (f32x4){0.f, 0.f, 0.f, 0.f};
#pragma unroll
        for (int n = 0; n < 4; ++n)
#pragma unroll
            for (int s = 0; s < 4; ++s) {
                short8 kf = *(const short8*)
                    &Kt[cur][n * 16 + l16][s * 32 + quad * 8];
                S[0][n] = mfma_bf16(qf[0][s], kf, S[0][n]);
                S[1][n] = mfma_bf16(qf[1][s], kf, S[1][n]);
            }

        // ---- fixed-shift softmax; P -> per-wave/per-tile LDS regions ----
        short8 pa[2][2];
#pragma unroll
        for (int rt = 0; rt < 2; ++rt) {
#pragma unroll
            for (int n = 0; n < 4; ++n)
#pragma unroll
                for (int r = 0; r < 4; ++r) {
                    float e = __builtin_amdgcn_exp2f(S[rt][n][r]);
                    lsum[rt][r] += e;
                    Plds[wave][rt][quad * 4 + r][n * 16 + l16] = f2bf(e);
                }
            pa[rt][0] = *(const short8*)&Plds[wave][rt][l16][quad * 8];
            pa[rt][1] = *(const short8*)&Plds[wave][rt][l16][32 + quad * 8];
        }

        // ---- O += P*V^T, both row-tiles share each V-fragment read ----
#pragma unroll
        for (int h = 0; h < 8; ++h) {
            short8 v0 = *(const short8*)&Vt[cur][h * 16 + l16][quad * 8];
            short8 v1 = *(const short8*)&Vt[cur][h * 16 + l16][32 + quad * 8];
            O[0][h] = mfma_bf16(pa[0][0], v0, O[0][h]);
            O[0][h] = mfma_bf16(pa[0][1], v1, O[0][h]);
            O[1][h] = mfma_bf16(pa[1][0], v0, O[1][h]);
            O[1][h] = mfma_bf16(pa[1][1], v1, O[1][h]);
        }

        if (it + 1 < NIT) {
            const int nxt = cur ^ 1;
#pragma unroll
            for (int j = 0; j < 4; ++j) {
                int ck = tid + 256 * j;
                *(uint4*)&Kt[nxt][ck >> 4][(ck & 15) * 8] = kst[j];
                *(uint4*)&Vt[nxt][ck >> 3][(ck & 7) * 8]  = vst[j];
            }
        }
    }

    // ---- row-sum reduction over 16 lanes; emit UNNORMALIZED partials ----
#pragma unroll
    for (int off = 1; off < 16; off <<= 1)
#pragma unroll
        for (int rt = 0; rt < 2; ++rt)
#pragma unroll
            for (int r = 0; r < 4; ++r)
                lsum[rt][r] += __shfl_xor(lsum[rt][r], off, 64);

#pragma unroll
    for (int rt = 0; rt < 2; ++rt)
#pragma unroll
        for (int r = 0; r < 4; ++r) {
            size_t row = (size_t)b * HW_DIM + q0 + rt * 16 + quad * 4 + r;
            if (l16 == 0) Lo[row] = lsum[rt][r];
#pragma unroll
            for (int h = 0; h < 8; ++h)
                Po[row * C_DIM + h * 16 + l16] = O[rt][h][r];
        }
}

// ---------------------------------------------------------------------------
extern "C" void kernel_launch(void* const* d_in, const int* in_sizes, int n_in,
                              void* d_out, int out_size, void* d_ws, size_t ws_size,
                              hipStream_t stream)
{
    const float* query = (const float*)d_in[0];
    const float* key   = (const float*)d_in[1];
    const float* q_w1 = (const float*)d_in[2];
    const float* q_g1 = (const float*)d_in[3];
    const float* q_b1 = (const float*)d_in[4];
    const float* q_w2 = (const float*)d_in[5];
    const float* q_g2 = (const float*)d_in[6];
    const float* q_b2 = (const float*)d_in[7];
    const float* k_w1 = (const float*)d_in[8];
    const float* k_g1 = (const float*)d_in[9];
    const float* k_b1 = (const float*)d_in[10];
    const float* k_w2 = (const float*)d_in[11];
    const float* k_g2 = (const float*)d_in[12];
    const float* k_b2 = (const float*)d_in[13];
    const float* v_w  = (const float*)d_in[14];
    const float* v_g  = (const float*)d_in[15];
    const float* v_b  = (const float*)d_in[16];
    const float* o_w  = (const float*)d_in[17];
    const float* o_g  = (const float*)d_in[18];
    const float* o_b  = (const float*)d_in[19];

    // workspace layout (y1 aliases P0: y1 dead before flash writes P0)
    char* ws = (char*)d_ws;
    float*          P0  = (float*)ws;                                   // 6 MB (also y1)
    float*          y1  = P0;
    unsigned short* Qbf = (unsigned short*)(ws + 6291456);              // 3 MB
    unsigned short* Kbf = (unsigned short*)(ws + 6291456 + 3145728);    // 3 MB
    unsigned short* Vbf = (unsigned short*)(ws + 6291456 + 2 * 3145728);// 3 MB
    float*          P1  = (float*)(ws + 6291456 + 3 * 3145728);         // 6 MB
    float*          L0  = (float*)(ws + 2 * 6291456 + 3 * 3145728);     // 48 KB
    float*          L1  = (float*)(ws + 2 * 6291456 + 3 * 3145728 + 49152);
    float* outp = (float*)d_out;

    const float qscale = 0.08838834764831845f * 1.44269504088896340f;

    dim3 cgrid(HW_DIM / 32, 2), cblk(256);
    hipLaunchKernelGGL((conv_bn_lrelu<0, 0>), cgrid, cblk, 0, stream,
                       query, nullptr, nullptr, nullptr,
                       q_w1, q_g1, q_b1, (void*)y1, nullptr, 1.0f);
    hipLaunchKernelGGL((conv_bn_lrelu<0, 1>), cgrid, cblk, 0, stream,
                       y1, nullptr, nullptr, nullptr,
                       q_w2, q_g2, q_b2, (void*)Qbf, nullptr, qscale);
    hipLaunchKernelGGL((conv_bn_lrelu<0, 0>), cgrid, cblk, 0, stream,
                       key, nullptr, nullptr, nullptr,
                       k_w1, k_g1, k_b1, (void*)y1, nullptr, 1.0f);
    hipLaunchKernelGGL((conv_bn_lrelu<0, 1>), cgrid, cblk, 0, stream,
                       y1, nullptr, nullptr, nullptr,
                       k_w2, k_g2, k_b2, (void*)Kbf, nullptr, 1.0f);
    hipLaunchKernelGGL((conv_bn_lrelu<0, 2>), cgrid, cblk, 0, stream,
                       key, nullptr, nullptr, nullptr,
                       v_w, v_g, v_b, (void*)Vbf, nullptr, 1.0f);

    // Flash: 128 q-rows/block x 2 k-halves, grid 192 (XCD-affine).
    hipLaunchKernelGGL(flash_attn, dim3(192), dim3(256), 0, stream,
                       Qbf, Kbf, Vbf, P0, P1, L0, L1);

    // Out-projection: combines split-K partials during staging + residual.
    hipLaunchKernelGGL((conv_bn_lrelu<2, 3>), cgrid, cblk, 0, stream,
                       P0, P1, L0, L1,
                       o_w, o_g, o_b, (void*)outp, query, 1.0f);
}